// Round 1
// baseline (106.418 us; speedup 1.0000x reference)
//
#include <hip/hip_runtime.h>
#include <math.h>
#include <stdint.h>

#define BQ 8
#define RR 1000
#define CC 1024
#define NCLS 81
#define NCP 96
#define HH 1024.0f
#define MIN_CONF_V 0.05f
#define NMS_THR_V 0.5f
#define NEGV -1e9f

#define BM 32
#define BK 32

// ---------------- Kernel 1: GEMM + softmax/argmax + delta2bbox ----------------
// grid 250 blocks x 512 threads. Each block: 32 rows, 96 (padded) cols, K=1024.
// lane mapping: r0 = lane%16 (rows r0, r0+16), q = lane/16, wave wq: cols wq*12+q*3+{0,1,2}
__global__ __launch_bounds__(512) void k1_head(
    const float* __restrict__ x, const float* __restrict__ w_cls,
    const float* __restrict__ b_cls, const float* __restrict__ w_delta,
    const float* __restrict__ b_delta, const float* __restrict__ rois,
    float* __restrict__ bx_ws, float* __restrict__ sc_ws, float* __restrict__ cid_ws)
{
    __shared__ float xs[BM][36];      // pad 36: 16B-aligned float4 rows, 2-way-bank max
    __shared__ float wsT[NCP][36];    // transposed w chunk: wsT[c][kk]
    __shared__ float outb[BM][100];   // full logits+deltas per row

    const int t = threadIdx.x;
    const int lane = t & 63;
    const int wq = t >> 6;            // 0..7
    const int r0 = lane & 15;
    const int q  = lane >> 4;         // 0..3
    const int c0 = wq * 12 + q * 3;   // 3 cols c0..c0+2
    const int row0 = blockIdx.x * BM;

    float acc0[3] = {0.f, 0.f, 0.f};
    float acc1[3] = {0.f, 0.f, 0.f};

    for (int k0 = 0; k0 < CC; k0 += BK) {
        // stage x tile (32 rows x 32 k), coalesced float4
        if (t < 256) {
            const int rr = t >> 3;
            const int kk = (t & 7) << 2;
            const float4 v = *reinterpret_cast<const float4*>(
                &x[(size_t)(row0 + rr) * CC + k0 + kk]);
            xs[rr][kk + 0] = v.x; xs[rr][kk + 1] = v.y;
            xs[rr][kk + 2] = v.z; xs[rr][kk + 3] = v.w;
        }
        // stage w chunk transposed (96 cols x 32 k); cols 81..84 = w_delta, >=85 zero
        #pragma unroll
        for (int i = 0; i < 6; ++i) {
            const int idx = i * 512 + t;       // 0..3071 = kk*96 + c
            const int kk = idx / NCP;
            const int c  = idx - kk * NCP;
            const int k  = k0 + kk;
            float v = 0.f;
            if (c < NCLS)            v = w_cls[(size_t)k * NCLS + c];
            else if (c < NCLS + 4)   v = w_delta[(size_t)k * 4 + (c - NCLS)];
            wsT[c][kk] = v;
        }
        __syncthreads();
        #pragma unroll
        for (int kk4 = 0; kk4 < BK; kk4 += 4) {
            const float4 xa = *reinterpret_cast<const float4*>(&xs[r0][kk4]);
            const float4 xb = *reinterpret_cast<const float4*>(&xs[r0 + 16][kk4]);
            #pragma unroll
            for (int j = 0; j < 3; ++j) {
                const float4 w4 = *reinterpret_cast<const float4*>(&wsT[c0 + j][kk4]);
                acc0[j] = fmaf(xa.x, w4.x, acc0[j]); acc0[j] = fmaf(xa.y, w4.y, acc0[j]);
                acc0[j] = fmaf(xa.z, w4.z, acc0[j]); acc0[j] = fmaf(xa.w, w4.w, acc0[j]);
                acc1[j] = fmaf(xb.x, w4.x, acc1[j]); acc1[j] = fmaf(xb.y, w4.y, acc1[j]);
                acc1[j] = fmaf(xb.z, w4.z, acc1[j]); acc1[j] = fmaf(xb.w, w4.w, acc1[j]);
            }
        }
        __syncthreads();
    }

    #pragma unroll
    for (int j = 0; j < 3; ++j) {
        outb[r0][c0 + j]      = acc0[j];
        outb[r0 + 16][c0 + j] = acc1[j];
    }
    __syncthreads();

    // epilogue: 16 threads per row (t/16 = row, t%16 = e), shfl groups contiguous
    {
        const int row = t >> 4;
        const int e = t & 15;
        float vmax = -INFINITY;
        int imax = 1 << 20;
        #pragma unroll
        for (int s = 0; s < 6; ++s) {
            const int c = e + 16 * s;
            if (c < NCLS) {
                const float v = outb[row][c] + b_cls[c];
                if (v > vmax) { vmax = v; imax = c; }   // first-argmax within lane
            }
        }
        #pragma unroll
        for (int m = 8; m >= 1; m >>= 1) {
            const float v2 = __shfl_xor(vmax, m);
            const int   i2 = __shfl_xor(imax, m);
            if (v2 > vmax || (v2 == vmax && i2 < imax)) { vmax = v2; imax = i2; }
        }
        float sume = 0.f;
        #pragma unroll
        for (int s = 0; s < 6; ++s) {
            const int c = e + 16 * s;
            if (c < NCLS) sume += expf(outb[row][c] + b_cls[c] - vmax);
        }
        #pragma unroll
        for (int m = 8; m >= 1; m >>= 1) sume += __shfl_xor(sume, m);

        if (e == 0) {
            const int gr = row0 + row;
            const float score = 1.0f / sume;     // exp(max-max)/sum
            const int cid = imax;
            const float d0 = (outb[row][81] + b_delta[0]) * 0.1f;
            const float d1 = (outb[row][82] + b_delta[1]) * 0.1f;
            const float d2 = (outb[row][83] + b_delta[2]) * 0.2f;
            const float d3 = (outb[row][84] + b_delta[3]) * 0.2f;
            const float y1 = rois[(size_t)gr * 5 + 1] * HH;
            const float x1 = rois[(size_t)gr * 5 + 2] * HH;
            const float y2 = rois[(size_t)gr * 5 + 3] * HH;
            const float x2 = rois[(size_t)gr * 5 + 4] * HH;
            const float h = y2 - y1, w = x2 - x1;
            const float cy = y1 + 0.5f * h + d0 * h;
            const float cx = x1 + 0.5f * w + d1 * w;
            const float h2 = h * expf(d2);
            const float w2 = w * expf(d3);
            const float by1 = fminf(fmaxf(cy - 0.5f * h2, 0.f), HH);
            const float bx1 = fminf(fmaxf(cx - 0.5f * w2, 0.f), HH);
            const float by2 = fminf(fmaxf(cy + 0.5f * h2, 0.f), HH);
            const float bx2 = fminf(fmaxf(cx + 0.5f * w2, 0.f), HH);
            const bool valid = (cid > 0) && (score >= MIN_CONF_V);
            bx_ws[(size_t)gr * 4 + 0] = by1;
            bx_ws[(size_t)gr * 4 + 1] = bx1;
            bx_ws[(size_t)gr * 4 + 2] = by2;
            bx_ws[(size_t)gr * 4 + 3] = bx2;
            sc_ws[gr]  = valid ? score : NEGV;
            cid_ws[gr] = (float)cid;
        }
    }
}

// ---------------- Kernel 2: per-batch stable sort + greedy NMS + emit ----------------
__global__ __launch_bounds__(1024) void k2_nms(
    const float* __restrict__ bx_ws, const float* __restrict__ sc_ws,
    const float* __restrict__ cid_ws, float* __restrict__ det)
{
    __shared__ unsigned long long keys[1024];
    __shared__ float sy1[1024], sx1[1024], sy2[1024], sx2[1024];
    __shared__ float scl[1024], ssc[1024];
    __shared__ unsigned char supp[1024];
    __shared__ int s_cnt;

    const int b = blockIdx.x;
    const int t = threadIdx.x;
    const int base = b * RR;

    // key = (order-preserving score bits << 32) | ~idx  -> stable desc argsort
    unsigned long long key = 0ull;
    if (t < RR) {
        const float s = sc_ws[base + t];
        unsigned int u = __float_as_uint(s);
        u = (u & 0x80000000u) ? ~u : (u | 0x80000000u);
        key = ((unsigned long long)u << 32) | (unsigned int)(~(unsigned int)t);
    }
    keys[t] = key;
    __syncthreads();

    // bitonic sort, descending
    for (int k = 2; k <= 1024; k <<= 1) {
        for (int j = k >> 1; j > 0; j >>= 1) {
            const int ixj = t ^ j;
            if (ixj > t) {
                const unsigned long long a = keys[t];
                const unsigned long long c = keys[ixj];
                const bool desc = ((t & k) == 0);
                if (desc ? (a < c) : (a > c)) { keys[t] = c; keys[ixj] = a; }
            }
            __syncthreads();
        }
    }

    // gather sorted entries
    const unsigned int lo = (unsigned int)keys[t];
    const int orig = (int)(~lo);
    float sv = NEGV;
    if (orig >= 0 && orig < RR) {
        const int g = base + orig;
        sy1[t] = bx_ws[(size_t)g * 4 + 0];
        sx1[t] = bx_ws[(size_t)g * 4 + 1];
        sy2[t] = bx_ws[(size_t)g * 4 + 2];
        sx2[t] = bx_ws[(size_t)g * 4 + 3];
        scl[t] = cid_ws[g];
        sv = sc_ws[g];
    } else {
        sy1[t] = sx1[t] = sy2[t] = sx2[t] = 0.f;
        scl[t] = -1.f;
    }
    ssc[t] = sv;
    supp[t] = 0;
    if (t == 0) s_cnt = 0;
    const int V = __syncthreads_count(sv > (NEGV * 0.5f));  // valid sorted first

    // greedy class-aware NMS, sequential over sorted order
    for (int i = 0; i < V; ++i) {
        __syncthreads();
        if (s_cnt >= 100) break;
        if (!supp[i]) {
            if (t > i && t < V && scl[t] == scl[i]) {
                const float yy1 = fmaxf(sy1[i], sy1[t]);
                const float xx1 = fmaxf(sx1[i], sx1[t]);
                const float yy2 = fminf(sy2[i], sy2[t]);
                const float xx2 = fminf(sx2[i], sx2[t]);
                const float inter = fmaxf(yy2 - yy1, 0.f) * fmaxf(xx2 - xx1, 0.f);
                const float ai = (sy2[i] - sy1[i]) * (sx2[i] - sx1[i]);
                const float at = (sy2[t] - sy1[t]) * (sx2[t] - sx1[t]);
                const float uni = ai + at - inter;
                if (inter / fmaxf(uni, 1e-8f) > NMS_THR_V) supp[t] = 1;
            }
            if (t == 0) {
                const int slot = s_cnt;
                if (slot < 100) {
                    float* o = det + ((size_t)b * 100 + slot) * 6;
                    o[0] = sy1[i]; o[1] = sx1[i]; o[2] = sy2[i]; o[3] = sx2[i];
                    o[4] = scl[i]; o[5] = ssc[i];
                }
                s_cnt = slot + 1;
            }
        }
    }
    __syncthreads();
    int cnt = s_cnt;
    if (cnt > 100) cnt = 100;
    for (int idx = t; idx < 600; idx += 1024) {
        if (idx >= cnt * 6) det[(size_t)b * 600 + idx] = 0.f;
    }
}

extern "C" void kernel_launch(void* const* d_in, const int* in_sizes, int n_in,
                              void* d_out, int out_size, void* d_ws, size_t ws_size,
                              hipStream_t stream) {
    const float* x       = (const float*)d_in[0];
    const float* w_cls   = (const float*)d_in[1];
    const float* b_cls   = (const float*)d_in[2];
    const float* w_delta = (const float*)d_in[3];
    const float* b_delta = (const float*)d_in[4];
    const float* rois    = (const float*)d_in[5];
    float* out = (float*)d_out;

    float* bx_ws  = (float*)d_ws;            // [8000][4]
    float* sc_ws  = bx_ws + 8000 * 4;        // [8000]
    float* cid_ws = sc_ws + 8000;            // [8000]

    k1_head<<<250, 512, 0, stream>>>(x, w_cls, b_cls, w_delta, b_delta, rois,
                                     bx_ws, sc_ws, cid_ws);
    k2_nms<<<8, 1024, 0, stream>>>(bx_ws, sc_ws, cid_ws, out);
}

// Round 2
// 63.933 us; speedup vs baseline: 1.6645x; 1.6645x over previous
//
#include <hip/hip_runtime.h>
#include <math.h>
#include <stdint.h>

#define RR 1000
#define CC 1024
#define NCLS 81
#define HH 1024.0f
#define MIN_CONF_V 0.05f
#define NMS_THR_V 0.5f
#define NEGV -1e9f

// ---------------- Kernel 0: transpose + pad weights -> wT[96][1024] ----------------
__global__ __launch_bounds__(256) void k0_wt(
    const float* __restrict__ w_cls, const float* __restrict__ w_delta,
    float* __restrict__ wT)
{
    const int c = blockIdx.x;     // 0..95
    const int t = threadIdx.x;
    for (int k = t; k < CC; k += 256) {
        float v = 0.f;
        if (c < NCLS)            v = w_cls[(size_t)k * NCLS + c];
        else if (c < NCLS + 4)   v = w_delta[(size_t)k * 4 + (c - NCLS)];
        wT[(size_t)c * CC + k] = v;
    }
}

// ---------------- Kernel 1: f32 GEMM (8000x96x1024) + softmax/argmax + bbox ----------------
// 250 blocks x 512 thr. Block tile: 32 rows x 96 cols. Per thread: 2 rows x 3 cols.
// LDS: double-buffered, XOR-swizzled, 64 KB exactly; epilogue aliases it.
__global__ __launch_bounds__(512) void k1_head(
    const float* __restrict__ x, const float* __restrict__ wT,
    const float* __restrict__ b_cls, const float* __restrict__ b_delta,
    const float* __restrict__ rois,
    float* __restrict__ bx_ws, float* __restrict__ sc_ws, float* __restrict__ cid_ws)
{
    __shared__ float4 smem4[4096];            // 64 KB
    float4* xs4 = smem4;                      // 2 x 512 float4  (32 rows x 64 k)
    float4* ws4 = smem4 + 1024;               // 2 x 1536 float4 (96 cols x 64 k)

    const int t = threadIdx.x;
    const int lane = t & 63;
    const int wq = t >> 6;                    // wave 0..7
    const int r0 = lane & 15;                 // row pair (r0, r0+16)
    const int q  = lane >> 4;                 // 0..3
    const int c0 = wq * 12 + q * 3;           // 3 cols c0..c0+2 (covers 0..95)
    const int row0 = blockIdx.x * 32;

    // staging: each thread 1 x-f4 + 3 w-f4 per chunk
    const int srow = t >> 4;                  // 0..31
    const int skg  = t & 15;                  // 0..15 (f4 slot in 64-float chunk)
    const size_t xsrc = (size_t)(row0 + srow) * CC + skg * 4;
    const int xdst = srow * 16 + (skg ^ (srow & 15));
    size_t wsrc0 = (size_t)(srow +  0) * CC + skg * 4;
    size_t wsrc1 = (size_t)(srow + 32) * CC + skg * 4;
    size_t wsrc2 = (size_t)(srow + 64) * CC + skg * 4;
    const int wdst0 = (srow +  0) * 16 + (skg ^ ((srow +  0) & 15));
    const int wdst1 = (srow + 32) * 16 + (skg ^ ((srow + 32) & 15));
    const int wdst2 = (srow + 64) * 16 + (skg ^ ((srow + 64) & 15));

    float acc00 = 0.f, acc01 = 0.f, acc02 = 0.f;
    float acc10 = 0.f, acc11 = 0.f, acc12 = 0.f;

    // prologue: chunk 0 -> regs
    float4 xv  = *(const float4*)(x  + xsrc);
    float4 wv0 = *(const float4*)(wT + wsrc0);
    float4 wv1 = *(const float4*)(wT + wsrc1);
    float4 wv2 = *(const float4*)(wT + wsrc2);

    const int xA = r0 * 16;
    const int xB = (r0 + 16) * 16;
    const int wB0 = (c0 + 0) * 16, wX0 = (c0 + 0) & 15;
    const int wB1 = (c0 + 1) * 16, wX1 = (c0 + 1) & 15;
    const int wB2 = (c0 + 2) * 16, wX2 = (c0 + 2) & 15;

    int cur = 0;
    for (int ch = 0; ch < 16; ++ch) {
        xs4[cur * 512  + xdst]  = xv;
        ws4[cur * 1536 + wdst0] = wv0;
        ws4[cur * 1536 + wdst1] = wv1;
        ws4[cur * 1536 + wdst2] = wv2;
        __syncthreads();
        if (ch < 15) {                        // issue next-chunk loads early (hide under compute)
            const size_t off = (size_t)(ch + 1) * 64;
            xv  = *(const float4*)(x  + xsrc + off);
            wv0 = *(const float4*)(wT + wsrc0 + off);
            wv1 = *(const float4*)(wT + wsrc1 + off);
            wv2 = *(const float4*)(wT + wsrc2 + off);
        }
        const float4* xsb = xs4 + cur * 512;
        const float4* wsb = ws4 + cur * 1536;
        #pragma unroll
        for (int kk = 0; kk < 16; ++kk) {
            const float4 xa = xsb[xA + (kk ^ r0)];
            const float4 xb = xsb[xB + (kk ^ r0)];
            const float4 w0 = wsb[wB0 + (kk ^ wX0)];
            const float4 w1 = wsb[wB1 + (kk ^ wX1)];
            const float4 w2 = wsb[wB2 + (kk ^ wX2)];
            acc00 = fmaf(xa.x, w0.x, acc00); acc00 = fmaf(xa.y, w0.y, acc00);
            acc00 = fmaf(xa.z, w0.z, acc00); acc00 = fmaf(xa.w, w0.w, acc00);
            acc01 = fmaf(xa.x, w1.x, acc01); acc01 = fmaf(xa.y, w1.y, acc01);
            acc01 = fmaf(xa.z, w1.z, acc01); acc01 = fmaf(xa.w, w1.w, acc01);
            acc02 = fmaf(xa.x, w2.x, acc02); acc02 = fmaf(xa.y, w2.y, acc02);
            acc02 = fmaf(xa.z, w2.z, acc02); acc02 = fmaf(xa.w, w2.w, acc02);
            acc10 = fmaf(xb.x, w0.x, acc10); acc10 = fmaf(xb.y, w0.y, acc10);
            acc10 = fmaf(xb.z, w0.z, acc10); acc10 = fmaf(xb.w, w0.w, acc10);
            acc11 = fmaf(xb.x, w1.x, acc11); acc11 = fmaf(xb.y, w1.y, acc11);
            acc11 = fmaf(xb.z, w1.z, acc11); acc11 = fmaf(xb.w, w1.w, acc11);
            acc12 = fmaf(xb.x, w2.x, acc12); acc12 = fmaf(xb.y, w2.y, acc12);
            acc12 = fmaf(xb.z, w2.z, acc12); acc12 = fmaf(xb.w, w2.w, acc12);
        }
        cur ^= 1;
    }
    __syncthreads();                          // everyone done reading buffers

    // epilogue: alias LDS as outb[32][104]
    float* outb = (float*)smem4;
    outb[r0 * 104 + c0 + 0] = acc00;
    outb[r0 * 104 + c0 + 1] = acc01;
    outb[r0 * 104 + c0 + 2] = acc02;
    outb[(r0 + 16) * 104 + c0 + 0] = acc10;
    outb[(r0 + 16) * 104 + c0 + 1] = acc11;
    outb[(r0 + 16) * 104 + c0 + 2] = acc12;
    __syncthreads();

    {
        const int row = t >> 4;               // 0..31
        const int e = t & 15;
        float vmax = -INFINITY;
        int imax = 1 << 20;
        #pragma unroll
        for (int s = 0; s < 6; ++s) {
            const int c = e + 16 * s;
            if (c < NCLS) {
                const float v = outb[row * 104 + c] + b_cls[c];
                if (v > vmax) { vmax = v; imax = c; }
            }
        }
        #pragma unroll
        for (int m = 8; m >= 1; m >>= 1) {
            const float v2 = __shfl_xor(vmax, m);
            const int   i2 = __shfl_xor(imax, m);
            if (v2 > vmax || (v2 == vmax && i2 < imax)) { vmax = v2; imax = i2; }
        }
        float sume = 0.f;
        #pragma unroll
        for (int s = 0; s < 6; ++s) {
            const int c = e + 16 * s;
            if (c < NCLS) sume += expf(outb[row * 104 + c] + b_cls[c] - vmax);
        }
        #pragma unroll
        for (int m = 8; m >= 1; m >>= 1) sume += __shfl_xor(sume, m);

        if (e == 0) {
            const int gr = row0 + row;
            const float score = 1.0f / sume;
            const int cid = imax;
            const float d0 = (outb[row * 104 + 81] + b_delta[0]) * 0.1f;
            const float d1 = (outb[row * 104 + 82] + b_delta[1]) * 0.1f;
            const float d2 = (outb[row * 104 + 83] + b_delta[2]) * 0.2f;
            const float d3 = (outb[row * 104 + 84] + b_delta[3]) * 0.2f;
            const float y1 = rois[(size_t)gr * 5 + 1] * HH;
            const float x1 = rois[(size_t)gr * 5 + 2] * HH;
            const float y2 = rois[(size_t)gr * 5 + 3] * HH;
            const float x2 = rois[(size_t)gr * 5 + 4] * HH;
            const float h = y2 - y1, w = x2 - x1;
            const float cy = y1 + 0.5f * h + d0 * h;
            const float cx = x1 + 0.5f * w + d1 * w;
            const float h2 = h * expf(d2);
            const float w2 = w * expf(d3);
            const float by1 = fminf(fmaxf(cy - 0.5f * h2, 0.f), HH);
            const float bx1 = fminf(fmaxf(cx - 0.5f * w2, 0.f), HH);
            const float by2 = fminf(fmaxf(cy + 0.5f * h2, 0.f), HH);
            const float bx2 = fminf(fmaxf(cx + 0.5f * w2, 0.f), HH);
            const bool valid = (cid > 0) && (score >= MIN_CONF_V);
            bx_ws[(size_t)gr * 4 + 0] = by1;
            bx_ws[(size_t)gr * 4 + 1] = bx1;
            bx_ws[(size_t)gr * 4 + 2] = by2;
            bx_ws[(size_t)gr * 4 + 3] = bx2;
            sc_ws[gr]  = valid ? score : NEGV;
            cid_ws[gr] = (float)cid;
        }
    }
}

// ---------------- Kernel 2: per-batch stable sort + greedy NMS + emit ----------------
__global__ __launch_bounds__(1024) void k2_nms(
    const float* __restrict__ bx_ws, const float* __restrict__ sc_ws,
    const float* __restrict__ cid_ws, float* __restrict__ det)
{
    __shared__ unsigned long long keys[1024];
    __shared__ float sy1[1024], sx1[1024], sy2[1024], sx2[1024];
    __shared__ float scl[1024], ssc[1024];
    __shared__ unsigned char supp[1024];
    __shared__ int s_cnt;

    const int b = blockIdx.x;
    const int t = threadIdx.x;
    const int base = b * RR;

    unsigned long long key = 0ull;
    if (t < RR) {
        const float s = sc_ws[base + t];
        unsigned int u = __float_as_uint(s);
        u = (u & 0x80000000u) ? ~u : (u | 0x80000000u);
        key = ((unsigned long long)u << 32) | (unsigned int)(~(unsigned int)t);
    }
    keys[t] = key;
    __syncthreads();

    for (int k = 2; k <= 1024; k <<= 1) {
        for (int j = k >> 1; j > 0; j >>= 1) {
            const int ixj = t ^ j;
            if (ixj > t) {
                const unsigned long long a = keys[t];
                const unsigned long long c = keys[ixj];
                const bool desc = ((t & k) == 0);
                if (desc ? (a < c) : (a > c)) { keys[t] = c; keys[ixj] = a; }
            }
            __syncthreads();
        }
    }

    const unsigned int lo = (unsigned int)keys[t];
    const int orig = (int)(~lo);
    float sv = NEGV;
    if (orig >= 0 && orig < RR) {
        const int g = base + orig;
        sy1[t] = bx_ws[(size_t)g * 4 + 0];
        sx1[t] = bx_ws[(size_t)g * 4 + 1];
        sy2[t] = bx_ws[(size_t)g * 4 + 2];
        sx2[t] = bx_ws[(size_t)g * 4 + 3];
        scl[t] = cid_ws[g];
        sv = sc_ws[g];
    } else {
        sy1[t] = sx1[t] = sy2[t] = sx2[t] = 0.f;
        scl[t] = -1.f;
    }
    ssc[t] = sv;
    supp[t] = 0;
    if (t == 0) s_cnt = 0;
    const int V = __syncthreads_count(sv > (NEGV * 0.5f));

    for (int i = 0; i < V; ++i) {
        __syncthreads();
        if (s_cnt >= 100) break;
        if (!supp[i]) {
            if (t > i && t < V && scl[t] == scl[i]) {
                const float yy1 = fmaxf(sy1[i], sy1[t]);
                const float xx1 = fmaxf(sx1[i], sx1[t]);
                const float yy2 = fminf(sy2[i], sy2[t]);
                const float xx2 = fminf(sx2[i], sx2[t]);
                const float inter = fmaxf(yy2 - yy1, 0.f) * fmaxf(xx2 - xx1, 0.f);
                const float ai = (sy2[i] - sy1[i]) * (sx2[i] - sx1[i]);
                const float at = (sy2[t] - sy1[t]) * (sx2[t] - sx1[t]);
                const float uni = ai + at - inter;
                if (inter / fmaxf(uni, 1e-8f) > NMS_THR_V) supp[t] = 1;
            }
            if (t == 0) {
                const int slot = s_cnt;
                if (slot < 100) {
                    float* o = det + ((size_t)b * 100 + slot) * 6;
                    o[0] = sy1[i]; o[1] = sx1[i]; o[2] = sy2[i]; o[3] = sx2[i];
                    o[4] = scl[i]; o[5] = ssc[i];
                }
                s_cnt = slot + 1;
            }
        }
    }
    __syncthreads();
    int cnt = s_cnt;
    if (cnt > 100) cnt = 100;
    for (int idx = t; idx < 600; idx += 1024) {
        if (idx >= cnt * 6) det[(size_t)b * 600 + idx] = 0.f;
    }
}

extern "C" void kernel_launch(void* const* d_in, const int* in_sizes, int n_in,
                              void* d_out, int out_size, void* d_ws, size_t ws_size,
                              hipStream_t stream) {
    const float* x       = (const float*)d_in[0];
    const float* w_cls   = (const float*)d_in[1];
    const float* b_cls   = (const float*)d_in[2];
    const float* w_delta = (const float*)d_in[3];
    const float* b_delta = (const float*)d_in[4];
    const float* rois    = (const float*)d_in[5];
    float* out = (float*)d_out;

    float* bx_ws  = (float*)d_ws;            // [8000][4]
    float* sc_ws  = bx_ws + 8000 * 4;        // [8000]
    float* cid_ws = sc_ws + 8000;            // [8000]
    float* wT     = cid_ws + 8000;           // [96][1024]

    k0_wt<<<96, 256, 0, stream>>>(w_cls, w_delta, wT);
    k1_head<<<250, 512, 0, stream>>>(x, wT, b_cls, b_delta, rois,
                                     bx_ws, sc_ws, cid_ws);
    k2_nms<<<8, 1024, 0, stream>>>(bx_ws, sc_ws, cid_ws, out);
}